// Round 4
// baseline (83.590 us; speedup 1.0000x reference)
//
#include <hip/hip_runtime.h>

#define C_CLASSES 1000
#define FEAT      128
#define MOM       0.9f

// ---------------- Two-level path ----------------
#define G       8                    // classes per block (== NWAVE: one wave drains one class)
#define NCG     (C_CLASSES / G)      // 125 class-groups
#define TPB     512                  // 8 waves
#define NWAVE   (TPB / 64)
#define S_SL    32                   // slices; ws need = S*C*(FEAT+1)*4 = 16.5 MB
#define QCAP    96                   // per-wave unified queue (mean ~15.6 at S=32, +20 sigma)
#define BQCAP   96                   // block per-class queue (mean ~15.6, +20 sigma)

__global__ __launch_bounds__(TPB) void ema_partial_kernel(
    const int* __restrict__ ids, const float* __restrict__ feats,
    float* __restrict__ ws_sum,   // [S][C][FEAT]
    float* __restrict__ ws_cnt,   // [S][C]
    int N)
{
    __shared__ int   qbuf[NWAVE][QCAP];     // 3 KB  per-wave unified queues
    __shared__ int   blkq[G][BQCAP];        // 3 KB  block-level per-class queues
    __shared__ float s_acc[G][FEAT];        // 4 KB  per-class sums (one wave each)
    __shared__ int   s_wcnt[NWAVE][G];      // per-wave per-class counts

    const int tid  = threadIdx.x;
    const int lane = tid & 63;
    const int wid  = tid >> 6;
    const int s    = blockIdx.x / NCG;      // slice-major: live slice hot in all L2s
    const int cg   = blockIdx.x % NCG;
    const int c0   = cg * G;
    const unsigned long long lmask_lt = (1ull << lane) - 1ull;

    // ---- Phase 1: scan slice, per-wave unified queue via ballot-prefix (no atomics)
    const int N4     = N >> 2;
    const int slice4 = (N4 + S_SL - 1) / S_SL;
    const int start4 = s * slice4;
    const int end4   = min(start4 + slice4, N4);
    const int iters  = (slice4 + TPB - 1) / TPB;
    const int4* ids4 = reinterpret_cast<const int4*>(ids);
    int qn = 0;                              // wave-uniform
    for (int k = 0; k < iters; ++k) {
        const int i4 = start4 + k * TPB + tid;
        int4 v;
        if (i4 < end4) v = ids4[i4];
        else           v = make_int4(-1, -1, -1, -1);
        const int idv[4] = {v.x, v.y, v.z, v.w};
#pragma unroll
        for (int j = 0; j < 4; ++j) {
            const unsigned g = (unsigned)idv[j] - (unsigned)c0;
            const bool m = (g < G);
            const unsigned long long bal = __ballot(m);
            if (bal) {
                if (m) {
                    const int slot = qn + __popcll(bal & lmask_lt);
                    if (slot < QCAP)
                        qbuf[wid][slot] = (((i4 << 2) | j) << 3) | (int)g;
                }
                qn += __popcll(bal);
            }
        }
    }
    // scalar tail (only if N % 4 != 0), owned by last slice
    if ((N & 3) && s == S_SL - 1) {
        for (int idx = (N4 << 2) + tid; idx < N + TPB; idx += TPB) {
            const int id = (idx < N) ? ids[idx] : -1;
            const unsigned g = (unsigned)id - (unsigned)c0;
            const bool m = (g < G);
            const unsigned long long bal = __ballot(m);
            if (bal) {
                if (m) {
                    const int slot = qn + __popcll(bal & lmask_lt);
                    if (slot < QCAP)
                        qbuf[wid][slot] = (idx << 3) | (int)g;
                }
                qn += __popcll(bal);
            }
        }
    }
    if (qn > QCAP) qn = QCAP;

    // ---- Phase 1.5a: count my wave's entries per class (ballot popcounts, uniform)
    int cw[G];
#pragma unroll
    for (int g = 0; g < G; ++g) cw[g] = 0;
    for (int base = 0; base < qn; base += 64) {
        const int qi = base + lane;
        const int e  = (qi < qn) ? qbuf[wid][qi] : -1;
        const unsigned gl = (e >= 0) ? (unsigned)(e & 7) : 0xffu;
#pragma unroll
        for (int g = 0; g < G; ++g)
            cw[g] += __popcll(__ballot(gl == (unsigned)g));
    }
    if (lane == 0) {
#pragma unroll
        for (int g = 0; g < G; ++g) s_wcnt[wid][g] = cw[g];
    }
    __syncthreads();

    // ---- Phase 1.5b: deterministic wave-major scatter into block per-class queues
    int off[G];
#pragma unroll
    for (int g = 0; g < G; ++g) {
        int o = 0;
#pragma unroll
        for (int w = 0; w < NWAVE; ++w)
            if (w < wid) o += s_wcnt[w][g];
        off[g] = o;
    }
    for (int base = 0; base < qn; base += 64) {
        const int qi = base + lane;
        const int e  = (qi < qn) ? qbuf[wid][qi] : -1;
        const unsigned gl = (e >= 0) ? (unsigned)(e & 7) : 0xffu;
#pragma unroll
        for (int g = 0; g < G; ++g) {
            const unsigned long long bal = __ballot(gl == (unsigned)g);
            if (gl == (unsigned)g) {
                const int slot = off[g] + __popcll(bal & lmask_lt);
                if (slot < BQCAP) blkq[g][slot] = e >> 3;
            }
            off[g] += __popcll(bal);
        }
    }
    __syncthreads();

    // ---- Phase 2: wave wid drains class wid — single accumulator, deep pipeline
    {
        const int g = wid;
        int tot = 0;
#pragma unroll
        for (int w = 0; w < NWAVE; ++w) tot += s_wcnt[w][g];
        const int nq = min(tot, BQCAP);

        const int half = lane >> 5;          // 0: even row of pair, 1: odd row
        const int col  = lane & 31;          // dims [col*4, col*4+3]
        float4 acc = make_float4(0.f, 0.f, 0.f, 0.f);
        int q = 0;
        for (; q + 8 <= nq; q += 8) {        // 4 independent 512B loads in flight
            const int r0 = blkq[g][q     + half];
            const int r1 = blkq[g][q + 2 + half];
            const int r2 = blkq[g][q + 4 + half];
            const int r3 = blkq[g][q + 6 + half];
            const float4 v0 = *reinterpret_cast<const float4*>(feats + (size_t)r0 * FEAT + col * 4);
            const float4 v1 = *reinterpret_cast<const float4*>(feats + (size_t)r1 * FEAT + col * 4);
            const float4 v2 = *reinterpret_cast<const float4*>(feats + (size_t)r2 * FEAT + col * 4);
            const float4 v3 = *reinterpret_cast<const float4*>(feats + (size_t)r3 * FEAT + col * 4);
            acc.x += v0.x + v1.x + v2.x + v3.x;
            acc.y += v0.y + v1.y + v2.y + v3.y;
            acc.z += v0.z + v1.z + v2.z + v3.z;
            acc.w += v0.w + v1.w + v2.w + v3.w;
        }
        for (; q + 2 <= nq; q += 2) {
            const int r = blkq[g][q + half];
            const float4 v = *reinterpret_cast<const float4*>(feats + (size_t)r * FEAT + col * 4);
            acc.x += v.x; acc.y += v.y; acc.z += v.z; acc.w += v.w;
        }
        if (q < nq) {                        // odd tail: only even-half contributes
            const int r = blkq[g][q];
            const float4 v = *reinterpret_cast<const float4*>(feats + (size_t)r * FEAT + col * 4);
            const float w = (half == 0) ? 1.f : 0.f;
            acc.x += v.x * w; acc.y += v.y * w; acc.z += v.z * w; acc.w += v.w * w;
        }
        // combine the two halves (even/odd rows)
        acc.x += __shfl_xor(acc.x, 32);
        acc.y += __shfl_xor(acc.y, 32);
        acc.z += __shfl_xor(acc.z, 32);
        acc.w += __shfl_xor(acc.w, 32);
        if (half == 0)
            *reinterpret_cast<float4*>(&s_acc[g][col * 4]) = acc;
    }
    __syncthreads();

    // ---- Write partials to workspace
    for (int gd = tid; gd < G * FEAT; gd += TPB) {
        const int g = gd >> 7;
        const int d = gd & 127;
        ws_sum[((size_t)s * C_CLASSES + (c0 + g)) * FEAT + d] = s_acc[g][d];
    }
    if (tid < G) {
        int tot = 0;
#pragma unroll
        for (int w = 0; w < NWAVE; ++w) tot += s_wcnt[w][tid];
        ws_cnt[(size_t)s * C_CLASSES + (c0 + tid)] = (float)min(tot, BQCAP);
    }
}

// ---------------- Kernel B: fixed-order slice reduce + EMA ----------------
__global__ __launch_bounds__(TPB) void ema_finalize_kernel(
    const float* __restrict__ ws_sum, const float* __restrict__ ws_cnt,
    const float* __restrict__ vec, const int* __restrict__ cnt,
    float* __restrict__ out, int S)
{
    const int t = blockIdx.x * TPB + threadIdx.x;
    if (t >= C_CLASSES * FEAT) return;
    const int c = t >> 7;
    const int d = t & 127;
    float sum = 0.f, cf = 0.f;
    for (int s = 0; s < S; ++s) {
        sum += ws_sum[((size_t)s * C_CLASSES + c) * FEAT + d];
        cf  += ws_cnt[(size_t)s * C_CLASSES + c];
    }
    const float old = vec[t];
    const int   oc  = cnt[c];
    const float mu  = sum / fmaxf(cf, 1.f);
    const float ema = (oc == 0) ? mu : (MOM * old + (1.0f - MOM) * mu);
    out[t] = (cf > 0.f) ? ema : old;
    if (d == 0)
        out[C_CLASSES * FEAT + c] = (float)(oc + (int)cf);
}

// ---------------- Fallback single-kernel path (tiny/absent workspace) ----------------
#define G_F     4
#define QCAP_F  768

__global__ __launch_bounds__(TPB) void ema_proto_kernel(
    const int* __restrict__ ids, const float* __restrict__ feats,
    const float* __restrict__ vec, const int* __restrict__ cnt,
    float* __restrict__ out, int N)
{
    __shared__ int   qbuf[NWAVE][QCAP_F];
    __shared__ float s_acc[NWAVE][G_F][FEAT];
    __shared__ float s_n[NWAVE][G_F];

    const int tid  = threadIdx.x;
    const int lane = tid & 63;
    const int wid  = tid >> 6;
    const int c0   = blockIdx.x * G_F;
    const unsigned long long lmask_lt = (1ull << lane) - 1ull;

    const int N4    = N >> 2;
    const int iters = (N4 + TPB - 1) / TPB;
    const int4* ids4 = reinterpret_cast<const int4*>(ids);
    int qn = 0;
    for (int k = 0; k < iters; ++k) {
        const int i4 = tid + k * TPB;
        int4 v;
        if (i4 < N4) v = ids4[i4];
        else         v = make_int4(-1, -1, -1, -1);
        const int idv[4] = {v.x, v.y, v.z, v.w};
#pragma unroll
        for (int j = 0; j < 4; ++j) {
            const unsigned g = (unsigned)idv[j] - (unsigned)c0;
            const bool m = (g < G_F);
            const unsigned long long bal = __ballot(m);
            if (bal) {
                if (m) {
                    const int slot = qn + __popcll(bal & lmask_lt);
                    if (slot < QCAP_F)
                        qbuf[wid][slot] = (((i4 << 2) | j) << 2) | (int)g;
                }
                qn += __popcll(bal);
            }
        }
    }
    if (qn > QCAP_F) qn = QCAP_F;

    float2 a[G_F];
    float  n[G_F];
#pragma unroll
    for (int g = 0; g < G_F; ++g) { a[g].x = 0.f; a[g].y = 0.f; n[g] = 0.f; }
    const int qn_pad = (qn + 3) & ~3;
    for (int q = 0; q < qn_pad; q += 4) {
#pragma unroll
        for (int u = 0; u < 4; ++u) {
            const int  qi   = q + u;
            const bool val  = (qi < qn);
            const int  pack = val ? qbuf[wid][qi] : 0;
            const int  row  = pack >> 2;
            const unsigned g = (unsigned)(pack & 3);
            const float w = val ? 1.f : 0.f;
            const float2 fv = *reinterpret_cast<const float2*>(
                feats + (size_t)row * FEAT + lane * 2);
#pragma unroll
            for (int k = 0; k < G_F; ++k) {
                const float wk = (g == (unsigned)k) ? w : 0.f;
                a[k].x += fv.x * wk;
                a[k].y += fv.y * wk;
                n[k]   += wk;
            }
        }
    }

#pragma unroll
    for (int g = 0; g < G_F; ++g)
        *reinterpret_cast<float2*>(&s_acc[wid][g][lane * 2]) = a[g];
    if (lane == 0) {
#pragma unroll
        for (int g = 0; g < G_F; ++g) s_n[wid][g] = n[g];
    }
    __syncthreads();

    {
        const int g = tid >> 7;
        const int d = tid & 127;
        float sum = 0.f, cf = 0.f;
#pragma unroll
        for (int w = 0; w < NWAVE; ++w) {
            sum += s_acc[w][g][d];
            cf  += s_n[w][g];
        }
        const int c = c0 + g;
        const float old = vec[c * FEAT + d];
        const int   oc  = cnt[c];
        const float mu  = sum / fmaxf(cf, 1.f);
        const float ema = (oc == 0) ? mu : (MOM * old + (1.0f - MOM) * mu);
        out[c * FEAT + d] = (cf > 0.f) ? ema : old;
        if (d == 0)
            out[C_CLASSES * FEAT + c] = (float)(oc + (int)cf);
    }
}

extern "C" void kernel_launch(void* const* d_in, const int* in_sizes, int n_in,
                              void* d_out, int out_size, void* d_ws, size_t ws_size,
                              hipStream_t stream) {
    const int*   ids   = (const int*)d_in[0];
    const float* feats = (const float*)d_in[1];
    const float* vec   = (const float*)d_in[2];
    const int*   cnt   = (const int*)d_in[3];
    float*       out   = (float*)d_out;
    const int N = in_sizes[0];

    const size_t need = (size_t)S_SL * C_CLASSES * (FEAT + 1) * sizeof(float);
    if (ws_size >= need) {
        float* ws_sum = (float*)d_ws;                                   // [S][C][FEAT]
        float* ws_cnt = ws_sum + (size_t)S_SL * C_CLASSES * FEAT;       // [S][C]
        hipLaunchKernelGGL(ema_partial_kernel, dim3(NCG * S_SL), dim3(TPB), 0, stream,
                           ids, feats, ws_sum, ws_cnt, N);
        hipLaunchKernelGGL(ema_finalize_kernel,
                           dim3((C_CLASSES * FEAT + TPB - 1) / TPB), dim3(TPB), 0, stream,
                           ws_sum, ws_cnt, vec, cnt, out, S_SL);
    } else {
        hipLaunchKernelGGL(ema_proto_kernel, dim3(C_CLASSES / G_F), dim3(TPB), 0, stream,
                           ids, feats, vec, cnt, out, N);
    }
}

// Round 5
// 59.019 us; speedup vs baseline: 1.4163x; 1.4163x over previous
//
#include <hip/hip_runtime.h>

#define C_CLASSES 1000
#define FEAT      128
#define MOM       0.9f
#define CAP       1024           // per-class slot capacity in sorted[] (max count ~580)
#define CHUNK     4096           // ids per scatter block
#define TPB_S     512            // scatter threads (8 ids/thread)
#define TPB_G     512            // gather threads (8 waves)

// ---------------- K0: zero the per-class cursors ----------------
__global__ __launch_bounds__(1024) void zero_cursor_kernel(int* __restrict__ cursor) {
    const int t = threadIdx.x;
    if (t < C_CLASSES) cursor[t] = 0;
}

// ---------------- K1: counting-scatter ids into class-sorted order ----------------
// Each block: LDS histogram of its 4096-id chunk -> one global atomicAdd per
// class for the block's base -> LDS-cursor ranks -> write row indices.
__global__ __launch_bounds__(TPB_S) void class_scatter_kernel(
    const int* __restrict__ ids, int* __restrict__ cursor,
    int* __restrict__ sorted, int N)
{
    __shared__ int hist[C_CLASSES];
    __shared__ int bb[C_CLASSES];
    __shared__ int cur[C_CLASSES];

    const int tid = threadIdx.x;
    for (int c = tid; c < C_CLASSES; c += TPB_S) { hist[c] = 0; cur[c] = 0; }
    __syncthreads();

    const int base = blockIdx.x * CHUNK + tid * 8;
    int myid[8];
    if (base + 8 <= N) {
        const int4 a = *reinterpret_cast<const int4*>(ids + base);
        const int4 b = *reinterpret_cast<const int4*>(ids + base + 4);
        myid[0] = a.x; myid[1] = a.y; myid[2] = a.z; myid[3] = a.w;
        myid[4] = b.x; myid[5] = b.y; myid[6] = b.z; myid[7] = b.w;
    } else {
#pragma unroll
        for (int j = 0; j < 8; ++j)
            myid[j] = (base + j < N) ? ids[base + j] : -1;
    }
#pragma unroll
    for (int j = 0; j < 8; ++j)
        if ((unsigned)myid[j] < (unsigned)C_CLASSES) atomicAdd(&hist[myid[j]], 1);
    __syncthreads();

    for (int c = tid; c < C_CLASSES; c += TPB_S) {
        const int h = hist[c];
        bb[c] = h ? atomicAdd(&cursor[c], h) : 0;
    }
    __syncthreads();

#pragma unroll
    for (int j = 0; j < 8; ++j) {
        const int c = myid[j];
        if ((unsigned)c < (unsigned)C_CLASSES) {
            const int r   = atomicAdd(&cur[c], 1);
            const int pos = bb[c] + r;
            if (pos < CAP) sorted[c * CAP + pos] = base + j;
        }
    }
}

// ---------------- K2: one class per block — gather rows, sum, EMA, write ----------------
__global__ __launch_bounds__(TPB_G) void gather_ema_kernel(
    const float* __restrict__ feats, const int* __restrict__ sorted,
    const int* __restrict__ cursor, const float* __restrict__ vec,
    const int* __restrict__ cnt, float* __restrict__ out)
{
    __shared__ float s_red[TPB_G / 64][FEAT];   // 4 KB

    const int c     = blockIdx.x;
    const int tid   = threadIdx.x;
    const int lane  = tid & 63;
    const int wid   = tid >> 6;
    const int half  = lane >> 5;      // pair member: 0 = even pos, 1 = odd pos
    const int col   = lane & 31;      // dims [col*4, col*4+3]

    const int n_raw = cursor[c];
    const int n     = min(n_raw, CAP);
    const int* sc   = sorted + c * CAP;

    // wave wid owns a contiguous run [w0, w1)
    const int q  = (n + (TPB_G / 64) - 1) / (TPB_G / 64);
    const int w0 = wid * q;
    const int w1 = min(w0 + q, n);
    const int m  = (w1 > w0) ? (w1 - w0) : 0;

    float4 acc = make_float4(0.f, 0.f, 0.f, 0.f);
    int p = 0;
    // deep pipeline: 8 paired-row float4 loads in flight (16 rows / iter)
    for (; p + 16 <= m; p += 16) {
        int idx[8];
#pragma unroll
        for (int u = 0; u < 8; ++u) idx[u] = sc[w0 + p + u * 2 + half];
#pragma unroll
        for (int u = 0; u < 8; ++u) {
            const float4 v = *reinterpret_cast<const float4*>(
                feats + (size_t)idx[u] * FEAT + col * 4);
            acc.x += v.x; acc.y += v.y; acc.z += v.z; acc.w += v.w;
        }
    }
    for (; p + 2 <= m; p += 2) {
        const int r = sc[w0 + p + half];
        const float4 v = *reinterpret_cast<const float4*>(
            feats + (size_t)r * FEAT + col * 4);
        acc.x += v.x; acc.y += v.y; acc.z += v.z; acc.w += v.w;
    }
    if (p < m) {                       // odd tail: only even-half contributes
        const int r = sc[w0 + p];
        const float4 v = *reinterpret_cast<const float4*>(
            feats + (size_t)r * FEAT + col * 4);
        const float w = (half == 0) ? 1.f : 0.f;
        acc.x += v.x * w; acc.y += v.y * w; acc.z += v.z * w; acc.w += v.w * w;
    }

    // combine pair halves, park per-wave sums in LDS
    acc.x += __shfl_xor(acc.x, 32);
    acc.y += __shfl_xor(acc.y, 32);
    acc.z += __shfl_xor(acc.z, 32);
    acc.w += __shfl_xor(acc.w, 32);
    if (half == 0)
        *reinterpret_cast<float4*>(&s_red[wid][col * 4]) = acc;
    __syncthreads();

    if (tid < FEAT) {
        float sum = 0.f;
#pragma unroll
        for (int w = 0; w < TPB_G / 64; ++w) sum += s_red[w][tid];
        const float old = vec[c * FEAT + tid];
        const int   oc  = cnt[c];
        const float mu  = sum / fmaxf((float)n_raw, 1.f);
        const float ema = (oc == 0) ? mu : (MOM * old + (1.0f - MOM) * mu);
        out[c * FEAT + tid] = (n_raw > 0) ? ema : old;
    }
    if (tid == FEAT)
        out[C_CLASSES * FEAT + c] = (float)(cnt[c] + n_raw);
}

// ---------------- Fallback single-kernel path (tiny/absent workspace) ----------------
#define G_F     4
#define QCAP_F  768
#define TPB_F   512
#define NWAVE_F (TPB_F / 64)

__global__ __launch_bounds__(TPB_F) void ema_proto_kernel(
    const int* __restrict__ ids, const float* __restrict__ feats,
    const float* __restrict__ vec, const int* __restrict__ cnt,
    float* __restrict__ out, int N)
{
    __shared__ int   qbuf[NWAVE_F][QCAP_F];
    __shared__ float s_acc[NWAVE_F][G_F][FEAT];
    __shared__ float s_n[NWAVE_F][G_F];

    const int tid  = threadIdx.x;
    const int lane = tid & 63;
    const int wid  = tid >> 6;
    const int c0   = blockIdx.x * G_F;
    const unsigned long long lmask_lt = (1ull << lane) - 1ull;

    const int N4    = N >> 2;
    const int iters = (N4 + TPB_F - 1) / TPB_F;
    const int4* ids4 = reinterpret_cast<const int4*>(ids);
    int qn = 0;
    for (int k = 0; k < iters; ++k) {
        const int i4 = tid + k * TPB_F;
        int4 v;
        if (i4 < N4) v = ids4[i4];
        else         v = make_int4(-1, -1, -1, -1);
        const int idv[4] = {v.x, v.y, v.z, v.w};
#pragma unroll
        for (int j = 0; j < 4; ++j) {
            const unsigned g = (unsigned)idv[j] - (unsigned)c0;
            const bool m = (g < G_F);
            const unsigned long long bal = __ballot(m);
            if (bal) {
                if (m) {
                    const int slot = qn + __popcll(bal & lmask_lt);
                    if (slot < QCAP_F)
                        qbuf[wid][slot] = (((i4 << 2) | j) << 2) | (int)g;
                }
                qn += __popcll(bal);
            }
        }
    }
    if (qn > QCAP_F) qn = QCAP_F;

    float2 a[G_F];
    float  n[G_F];
#pragma unroll
    for (int g = 0; g < G_F; ++g) { a[g].x = 0.f; a[g].y = 0.f; n[g] = 0.f; }
    const int qn_pad = (qn + 3) & ~3;
    for (int q = 0; q < qn_pad; q += 4) {
#pragma unroll
        for (int u = 0; u < 4; ++u) {
            const int  qi   = q + u;
            const bool val  = (qi < qn);
            const int  pack = val ? qbuf[wid][qi] : 0;
            const int  row  = pack >> 2;
            const unsigned g = (unsigned)(pack & 3);
            const float w = val ? 1.f : 0.f;
            const float2 fv = *reinterpret_cast<const float2*>(
                feats + (size_t)row * FEAT + lane * 2);
#pragma unroll
            for (int k = 0; k < G_F; ++k) {
                const float wk = (g == (unsigned)k) ? w : 0.f;
                a[k].x += fv.x * wk;
                a[k].y += fv.y * wk;
                n[k]   += wk;
            }
        }
    }

#pragma unroll
    for (int g = 0; g < G_F; ++g)
        *reinterpret_cast<float2*>(&s_acc[wid][g][lane * 2]) = a[g];
    if (lane == 0) {
#pragma unroll
        for (int g = 0; g < G_F; ++g) s_n[wid][g] = n[g];
    }
    __syncthreads();

    {
        const int g = tid >> 7;
        const int d = tid & 127;
        float sum = 0.f, cf = 0.f;
#pragma unroll
        for (int w = 0; w < NWAVE_F; ++w) {
            sum += s_acc[w][g][d];
            cf  += s_n[w][g];
        }
        const int c = c0 + g;
        const float old = vec[c * FEAT + d];
        const int   oc  = cnt[c];
        const float mu  = sum / fmaxf(cf, 1.f);
        const float ema = (oc == 0) ? mu : (MOM * old + (1.0f - MOM) * mu);
        out[c * FEAT + d] = (cf > 0.f) ? ema : old;
        if (d == 0)
            out[C_CLASSES * FEAT + c] = (float)(oc + (int)cf);
    }
}

extern "C" void kernel_launch(void* const* d_in, const int* in_sizes, int n_in,
                              void* d_out, int out_size, void* d_ws, size_t ws_size,
                              hipStream_t stream) {
    const int*   ids   = (const int*)d_in[0];
    const float* feats = (const float*)d_in[1];
    const float* vec   = (const float*)d_in[2];
    const int*   cnt   = (const int*)d_in[3];
    float*       out   = (float*)d_out;
    const int N = in_sizes[0];

    // ws layout: cursor[1024 ints] | sorted[C_CLASSES * CAP ints]
    const size_t need = (size_t)(1024 + C_CLASSES * CAP) * sizeof(int);
    if (ws_size >= need) {
        int* cursor = (int*)d_ws;
        int* sorted = cursor + 1024;
        hipLaunchKernelGGL(zero_cursor_kernel, dim3(1), dim3(1024), 0, stream, cursor);
        const int nblk = (N + CHUNK - 1) / CHUNK;
        hipLaunchKernelGGL(class_scatter_kernel, dim3(nblk), dim3(TPB_S), 0, stream,
                           ids, cursor, sorted, N);
        hipLaunchKernelGGL(gather_ema_kernel, dim3(C_CLASSES), dim3(TPB_G), 0, stream,
                           feats, sorted, cursor, vec, cnt, out);
    } else {
        hipLaunchKernelGGL(ema_proto_kernel, dim3(C_CLASSES / G_F), dim3(TPB_F), 0, stream,
                           ids, feats, vec, cnt, out, N);
    }
}